// Round 6
// baseline (160.315 us; speedup 1.0000x reference)
//
#include <hip/hip_runtime.h>
#include <cstdint>
#include <cstddef>

// Problem constants
#define B_    128   // batch
#define C_    32    // in channels
#define O_    64    // out channels
#define H_    34    // input H=W (34 = 32+2)
#define NPOS  1024  // 32*32 spatial positions
#define K9    9     // 3x3 taps
#define BC    (B_ * C_)   // 4096
#define BO    (B_ * O_)   // 8192
#define NPK   (NPOS * K9) // 9216 floats per (o,c) weight row

typedef __bf16 v8bf __attribute__((ext_vector_type(8)));
typedef float  v4f  __attribute__((ext_vector_type(4)));
typedef float  f4a  __attribute__((ext_vector_type(4)));              // 16-B aligned float4

__device__ __forceinline__ unsigned short f2bf(float f) {
    union { float f; unsigned int u; } v; v.f = f;
    unsigned int u = v.u;
    return (unsigned short)((u + 0x7FFFu + ((u >> 16) & 1u)) >> 16);
}

// ---------------------------------------------------------------------------
// Pass 1: repack x (fp32 [b][c][34][34]) -> x2 (bf16 [h][w][b][c]).
// Block = (b-pair, h-pair); 272-B contiguous reads per (b,c), float2 loads,
// transposed LDS tile, ushort2 stores.  [unchanged]
// ---------------------------------------------------------------------------
__global__ __launch_bounds__(256) void repack_x(const float* __restrict__ x,
                                                unsigned short* __restrict__ x2) {
    const int bq = blockIdx.x / 17;      // b-pair 0..63
    const int hp = blockIdx.x % 17;      // h-pair 0..16
    const int b0 = bq * 2;
    const int h0 = hp * 2;
    __shared__ unsigned short tile[2][H_][66];   // [hh][w][bb*32+c] (+2 pad)
    const int t = threadIdx.x;

    for (int e = t; e < 2176; e += 256) {
        const int bb  = e / 1088;
        const int rem = e % 1088;
        const int c   = rem / 34;
        const int wp  = rem % 34;        // float2 index within the 68-float run
        const float2 v = *(const float2*)(x +
            ((size_t)((b0 + bb) * C_ + c) * H_ + h0) * H_ + wp * 2);
        const int hh = (wp >= 17) ? 1 : 0;
        const int w  = wp * 2 - hh * 34;
        const int idx = bb * 32 + c;
        tile[hh][w][idx]     = f2bf(v.x);
        tile[hh][w + 1][idx] = f2bf(v.y);
    }
    __syncthreads();

    for (int e = t; e < 2176; e += 256) {
        const int hh  = e / 1088;
        const int rem = e % 1088;
        const int w   = rem >> 5;
        const int i2  = rem & 31;
        ushort2 pk;
        pk.x = tile[hh][w][i2 * 2];
        pk.y = tile[hh][w][i2 * 2 + 1];
        *(ushort2*)(x2 + (size_t)((h0 + hh) * H_ + w) * BC + bq * 64 + i2 * 2) = pk;
    }
}

// ---------------------------------------------------------------------------
// Main (v7): minimize TOTAL vector-memory bytes (the measured 4.5-5 TB/s
// L1-path ceiling governs, not HBM).  Block = (i, 4-j), FULL 64 o, 512 thr.
// Per block: wt 295 KB + x2 144 KB + out 131 KB = 570 KB (-37% vs v2):
//  - full-o kills the 4x oq re-read of x2 (123 MB -> 37 MB total),
//  - 16-b waves (8 waves x 16 b = 128 b) kill the 2x mt ax duplication,
//  - each ax load feeds 4 nt B-fragments from LDS (reuse is free in LDS).
// Weight image: 36 d-rows (d=jj*9+tap) x 2048 pl (pl=o*32+c) bf16 = 147 KB,
// col swizzle ((pl>>3)^(d4&7))*8+(pl&7), d4=d>>2 -> staging writes ~2-way
// banks, fragment reads dense contiguous 1 KB/wave (conflict-free).
// Staging: 18,432 (pl,d4) dwordx4 tasks, 36/thread in 3 batches of 12.
// Chunked XCD map: jq-siblings (which share each 64-B out line) adjacent on
// one XCD -> L2 write-merge of the 16-B quarter-line out runs.
// ---------------------------------------------------------------------------
__global__ __launch_bounds__(512, 1) void lc_fused6(const unsigned short* __restrict__ x2,
                                                    const float* __restrict__ weight,
                                                    const float* __restrict__ bias,
                                                    float* __restrict__ out) {
    __shared__ __align__(16) unsigned short Wl[36 * 2048];  // 147,456 B

    const int bid = blockIdx.x;
    const int lb  = (bid & 7) * 32 + (bid >> 3);   // bijective (256 % 8 == 0)
    const int i   = lb >> 3;            // 0..31
    const int jq  = lb & 7;             // 0..7  (4-j group)
    const int j0  = jq * 4;
    const int posbase = i * 32 + j0;    // multiple of 4 -> 16-B aligned out runs
    const int t = threadIdx.x;          // 0..511

    // ---- stage: 2048 pl x 36 floats (contiguous per pl); 36 tasks/thread ----
    const float* wbase = weight + (size_t)posbase * K9;
#pragma unroll
    for (int r = 0; r < 3; ++r) {
        f4a v[12];
#pragma unroll
        for (int m = 0; m < 12; ++m) {
            const int task = (r * 12 + m) * 512 + t;   // 0..18431
            const int pl = task / 9;
            const int d4 = task % 9;
            v[m] = *(const f4a*)(wbase + (size_t)pl * NPK + d4 * 4);
        }
#pragma unroll
        for (int m = 0; m < 12; ++m) {
            const int task = (r * 12 + m) * 512 + t;
            const int pl = task / 9;
            const int d4 = task % 9;
            const int col = (((pl >> 3) ^ (d4 & 7)) << 3) + (pl & 7);
#pragma unroll
            for (int u = 0; u < 4; ++u)
                Wl[(d4 * 4 + u) * 2048 + col] = f2bf(v[m][u]);
        }
    }
    __syncthreads();

    const int wv = t >> 6;      // wave -> b-band [wv*16, wv*16+16)
    const int l  = t & 63;
    const int lm = l & 15;      // A m-index (b) / B n-index (o within nt tile)
    const int q  = l >> 4;

    v4f acc[4][4];              // [jj][nt]
#pragma unroll
    for (int a = 0; a < 4; ++a)
#pragma unroll
        for (int n = 0; n < 4; ++n) acc[a][n] = (v4f){0.f, 0.f, 0.f, 0.f};

#pragma unroll
    for (int kh = 0; kh < 3; ++kh) {
        v8bf ax[6];
        const int rowbase = (i + kh) * H_ + j0;
#pragma unroll
        for (int w6 = 0; w6 < 6; ++w6) {
            const unsigned short* xrow = x2 + (size_t)(rowbase + w6) * BC;
            ax[w6] = *(const v8bf*)(xrow + (wv * 16 + lm) * C_ + q * 8);
        }
#pragma unroll
        for (int kw = 0; kw < 3; ++kw) {
            const int tap = kh * 3 + kw;
#pragma unroll
            for (int jj = 0; jj < 4; ++jj) {
                const int jk = jj * K9 + tap;          // d-row 0..35
                const int xr = (jk >> 2) & 7;
#pragma unroll
                for (int nt = 0; nt < 4; ++nt) {
                    const int p8 = (nt * 16 + lm) * 4 + q;       // 0..255
                    const v8bf bfr = *(const v8bf*)&Wl[jk * 2048 + ((p8 ^ xr) << 3)];
                    acc[jj][nt] = __builtin_amdgcn_mfma_f32_16x16x32_bf16(
                        ax[kw + jj], bfr, acc[jj][nt], 0, 0, 0);
                }
            }
        }
    }

    // ---- epilogue: fp32 out + bias; 16-B aligned 16-B runs per (b,o) ----
    // D layout: col = lane&15 -> o = nt*16+lm, row = q*4+r2 -> b = wv*16+q*4+r2
#pragma unroll
    for (int nt = 0; nt < 4; ++nt) {
        const int o = nt * 16 + lm;
        const f4a bv = *(const f4a*)(bias + (size_t)o * NPOS + posbase);
#pragma unroll
        for (int r2 = 0; r2 < 4; ++r2) {
            const int b = wv * 16 + q * 4 + r2;
            f4a val = {acc[0][nt][r2] + bv[0], acc[1][nt][r2] + bv[1],
                       acc[2][nt][r2] + bv[2], acc[3][nt][r2] + bv[3]};
            *(f4a*)(out + ((size_t)b * O_ + o) * NPOS + posbase) = val;
        }
    }
}

// ---------------------------------------------------------------------------
// Fallback (no workspace): per-pos kernel gathering straight from fp32.
// ---------------------------------------------------------------------------
__global__ __launch_bounds__(256) void lc_fallback(const float* __restrict__ x,
                                                   const float* __restrict__ weight,
                                                   const float* __restrict__ bias,
                                                   float* __restrict__ out) {
    const int pos = blockIdx.x;
    const int i = pos >> 5, j = pos & 31;
    const int t  = threadIdx.x;
    const int wv = t >> 6;
    const int l  = t & 63;
    const int lm = l & 15;
    const int q  = l >> 4;

    float bv[4];
#pragma unroll
    for (int nt = 0; nt < 4; ++nt)
        bv[nt] = bias[(size_t)(nt * 16 + lm) * NPOS + pos];

    v4f acc[2][4];
#pragma unroll
    for (int a = 0; a < 2; ++a)
#pragma unroll
        for (int n = 0; n < 4; ++n) acc[a][n] = (v4f){0.f, 0.f, 0.f, 0.f};

    for (int k = 0; k < K9; ++k) {
        const int kh = k / 3, kw = k % 3;
        v8bf af[2], bfr[4];
#pragma unroll
        for (int mt = 0; mt < 2; ++mt) {
            const int b = wv * 32 + mt * 16 + lm;
            union { v8bf v; unsigned short s[8]; } u;
#pragma unroll
            for (int cc = 0; cc < 8; ++cc)
                u.s[cc] = f2bf(x[(((size_t)b * C_ + q * 8 + cc) * H_ + (i + kh)) * H_ + (j + kw)]);
            af[mt] = u.v;
        }
#pragma unroll
        for (int nt = 0; nt < 4; ++nt) {
            union { v8bf v; unsigned short s[8]; } u;
#pragma unroll
            for (int cc = 0; cc < 8; ++cc) {
                const int p = (nt * 16 + lm) * C_ + q * 8 + cc;
                u.s[cc] = f2bf(weight[((size_t)p * NPOS + pos) * K9 + k]);
            }
            bfr[nt] = u.v;
        }
#pragma unroll
        for (int mt = 0; mt < 2; ++mt)
#pragma unroll
            for (int nt = 0; nt < 4; ++nt)
                acc[mt][nt] = __builtin_amdgcn_mfma_f32_16x16x32_bf16(
                    af[mt], bfr[nt], acc[mt][nt], 0, 0, 0);
    }
#pragma unroll
    for (int mt = 0; mt < 2; ++mt)
#pragma unroll
        for (int nt = 0; nt < 4; ++nt) {
            const int o = nt * 16 + lm;
#pragma unroll
            for (int r = 0; r < 4; ++r) {
                const int b = wv * 32 + mt * 16 + q * 4 + r;
                out[(size_t)(b * O_ + o) * NPOS + pos] = acc[mt][nt][r] + bv[nt];
            }
        }
}

// ---------------------------------------------------------------------------
extern "C" void kernel_launch(void* const* d_in, const int* in_sizes, int n_in,
                              void* d_out, int out_size, void* d_ws, size_t ws_size,
                              hipStream_t stream) {
    const float* x      = (const float*)d_in[0];
    const float* weight = (const float*)d_in[1];
    const float* bias   = (const float*)d_in[2];
    float* out          = (float*)d_out;

    const size_t X2B = (size_t)H_ * H_ * BC * sizeof(unsigned short);     // 9,469,952

    if (ws_size >= X2B) {
        unsigned short* x2 = (unsigned short*)d_ws;
        repack_x<<<64 * 17, 256, 0, stream>>>(x, x2);
        lc_fused6<<<256, 512, 0, stream>>>(x2, weight, bias, out);
    } else {
        lc_fallback<<<NPOS, 256, 0, stream>>>(x, weight, bias, out);
    }
}